// Round 1
// baseline (689.631 us; speedup 1.0000x reference)
//
#include <hip/hip_runtime.h>
#include <hip/hip_bf16.h>

// KroneckerMixer: B=64, N=1024, K=64, BASIS=8, T=0.2, 20 sinkhorn iters.
// Pipeline:
//   k_sinkA : multiplicative Sinkhorn-Knopp on exp(A_logits/T), grid-barrier based.
//             Produces A[1024][1024] fp32 in ws.
//   k_wpath : per-n (1024 blocks): W_logits = W1[n]@W_V, local sinkhorn (reg-resident,
//             DPP wave reductions), then x_local = x[:,n,:] @ W[n]; writes
//             XL[n][b*64+o] (transposed layout) in ws.
//   k_gemm  : out[b][m*64+o] = sum_n A[m][n] * XL[n][b*64+o]  (fp32 tiled GEMM).

#define N_DIM 1024
#define INV_T 5.0f

// ---------------- wave64 sum reduction via DPP (VALU pipe) -------------------
// Result valid in lane 63.
__device__ __forceinline__ float wave_red_sum(float x) {
#define DPP_ADD(C)                                                            \
  {                                                                           \
    int _y = __builtin_amdgcn_update_dpp(0, __float_as_int(x), (C), 0xf, 0xf, \
                                         true);                               \
    x += __int_as_float(_y);                                                  \
  }
  DPP_ADD(0x111);  // row_shr:1
  DPP_ADD(0x112);  // row_shr:2
  DPP_ADD(0x114);  // row_shr:4
  DPP_ADD(0x118);  // row_shr:8
  DPP_ADD(0x142);  // row_bcast:15
  DPP_ADD(0x143);  // row_bcast:31
#undef DPP_ADD
  return x;
}

// ---------------- device-scope grid barrier ---------------------------------
__device__ __forceinline__ void gbar(unsigned* cnt, unsigned* gen,
                                     unsigned nblk) {
  __syncthreads();
  if (threadIdx.x == 0) {
    __threadfence();
    unsigned g = __hip_atomic_load(gen, __ATOMIC_RELAXED,
                                   __HIP_MEMORY_SCOPE_AGENT);
    unsigned a = __hip_atomic_fetch_add(cnt, 1u, __ATOMIC_ACQ_REL,
                                        __HIP_MEMORY_SCOPE_AGENT);
    if (a == nblk - 1u) {
      __hip_atomic_store(cnt, 0u, __ATOMIC_RELAXED, __HIP_MEMORY_SCOPE_AGENT);
      __hip_atomic_fetch_add(gen, 1u, __ATOMIC_RELEASE,
                             __HIP_MEMORY_SCOPE_AGENT);
    } else {
      unsigned cur;
      do {
        __builtin_amdgcn_s_sleep(1);
        cur = __hip_atomic_load(gen, __ATOMIC_ACQUIRE,
                                __HIP_MEMORY_SCOPE_AGENT);
      } while (cur == g);
    }
    __threadfence();
  }
  __syncthreads();
}

// ---------------- kernel 1: A sinkhorn ---------------------------------------
// 64 blocks x 1024 threads. Block b owns rows r0..r0+15.
// Two register layouts of E0 = exp(L/T):
//   e_r[16]: row (r0 + wave), cols lane*16 + j   (row-pass: thread-local partial)
//   e_c[16]: col t, rows r0..r0+15               (col-pass: thread-local partial)
__global__ __launch_bounds__(1024) void k_sinkA(
    const float* __restrict__ L, float* __restrict__ A, float* __restrict__ P,
    float* __restrict__ v, unsigned* __restrict__ ctrl) {
  __shared__ float uS[16];
  const int t = threadIdx.x;
  const int b = blockIdx.x;  // 64
  const int r0 = b * 16;
  const int lane = t & 63;
  const int w = t >> 6;  // 0..15
  unsigned* cnt = ctrl;
  unsigned* gen = ctrl + 1;

  float e_c[16];
#pragma unroll
  for (int i = 0; i < 16; ++i)
    e_c[i] = __expf(L[(r0 + i) * N_DIM + t] * INV_T);

  float e_r[16];
  {
    const float4* src = (const float4*)(L + (size_t)(r0 + w) * N_DIM + lane * 16);
#pragma unroll
    for (int q = 0; q < 4; ++q) {
      float4 f = src[q];
      e_r[4 * q + 0] = __expf(f.x * INV_T);
      e_r[4 * q + 1] = __expf(f.y * INV_T);
      e_r[4 * q + 2] = __expf(f.z * INV_T);
      e_r[4 * q + 3] = __expf(f.w * INV_T);
    }
  }

  for (int it = 0; it < 20; ++it) {
    // ---- row pass: u_m = 1 / sum_n E0[m][n] * v[n]
    float p = 0.f;
    if (it == 0) {
#pragma unroll
      for (int j = 0; j < 16; ++j) p += e_r[j];
    } else {
      const float4* vv = (const float4*)(v + lane * 16);
#pragma unroll
      for (int q = 0; q < 4; ++q) {
        float4 f = vv[q];
        p += e_r[4 * q + 0] * f.x + e_r[4 * q + 1] * f.y +
             e_r[4 * q + 2] * f.z + e_r[4 * q + 3] * f.w;
      }
    }
    p = wave_red_sum(p);
    if (lane == 63) uS[w] = 1.0f / p;
    __syncthreads();
    // ---- col pass partial: this block's 16 rows contribution to col t
    float cp = 0.f;
#pragma unroll
    for (int i = 0; i < 16; ++i) cp += e_c[i] * uS[i];
    P[t * 64 + b] = cp;
    gbar(cnt, gen, 64u);
    // ---- reduce partials: block b owns cols 16b..16b+15 (one per wave)
    {
      const int c = 16 * b + w;
      float s2 = P[c * 64 + lane];
      s2 = wave_red_sum(s2);
      if (lane == 63) v[c] = 1.0f / s2;
    }
    gbar(cnt, gen, 64u);
  }
  // ---- final A = E0 * u (x) v
  const float vt = v[t];
#pragma unroll
  for (int i = 0; i < 16; ++i)
    A[(size_t)(r0 + i) * N_DIM + t] = e_c[i] * uS[i] * vt;
}

// ---------------- kernel 2: W path + local mix -------------------------------
// 1024 blocks x 256 threads. Block n.
// Element f = j*256 + t  ->  row i = 4j + h (h = wave), col o = lane.
__global__ __launch_bounds__(256) void k_wpath(const float* __restrict__ x,
                                               const float* __restrict__ W1,
                                               const float* __restrict__ WV,
                                               float* __restrict__ XL) {
  __shared__ float uS[64];
  __shared__ float ps[4][64];
  __shared__ float Ws[64 * 64];
  __shared__ float Xs[64 * 65];
  const int n = blockIdx.x;
  const int t = threadIdx.x;
  const int lane = t & 63;
  const int h = t >> 6;

  float w1[8];
#pragma unroll
  for (int k = 0; k < 8; ++k) w1[k] = W1[n * 8 + k];

  float ew[16];
#pragma unroll
  for (int j = 0; j < 16; ++j) {
    const int f = j * 256 + t;
    float a = 0.f;
#pragma unroll
    for (int k = 0; k < 8; ++k) a += w1[k] * WV[k * 4096 + f];
    ew[j] = __expf(a * INV_T);
  }

  float vt = 1.0f;
  for (int it = 0; it < 20; ++it) {
    // row pass: wave h owns rows 4j+h entirely (64 cols = 64 lanes)
#pragma unroll
    for (int j = 0; j < 16; ++j) {
      float p = wave_red_sum(ew[j] * vt);
      if (lane == 63) uS[4 * j + h] = 1.0f / p;
    }
    __syncthreads();
    // col pass: thread-local over its 16 rows, then cross-wave via LDS
    float cp = 0.f;
#pragma unroll
    for (int j = 0; j < 16; ++j) cp += ew[j] * uS[4 * j + h];
    ps[h][lane] = cp;
    __syncthreads();
    vt = 1.0f / (ps[0][lane] + ps[1][lane] + ps[2][lane] + ps[3][lane]);
    __syncthreads();
  }

  // materialize W into LDS, stage x tile
#pragma unroll
  for (int j = 0; j < 16; ++j)
    Ws[(4 * j + h) * 64 + lane] = ew[j] * uS[4 * j + h] * vt;
#pragma unroll
  for (int j = 0; j < 16; ++j) {
    const int bb = 4 * j + h;
    Xs[bb * 65 + lane] = x[(size_t)bb * 65536 + n * 64 + lane];
  }
  __syncthreads();

  // x_local[b][o] = sum_i x[b][i] * W[i][o] ; thread tile 4b x 4o
  const int o4 = (t & 15) * 4;
  const int b4 = (t >> 4) * 4;
  float acc[4][4] = {};
#pragma unroll 4
  for (int i = 0; i < 64; ++i) {
    float4 w4 = *(const float4*)&Ws[i * 64 + o4];
#pragma unroll
    for (int bb = 0; bb < 4; ++bb) {
      float xv = Xs[(b4 + bb) * 65 + i];
      acc[bb][0] += xv * w4.x;
      acc[bb][1] += xv * w4.y;
      acc[bb][2] += xv * w4.z;
      acc[bb][3] += xv * w4.w;
    }
  }
#pragma unroll
  for (int bb = 0; bb < 4; ++bb)
    *(float4*)&XL[(size_t)n * 4096 + (b4 + bb) * 64 + o4] =
        *(float4*)&acc[bb][0];
}

// ---------------- kernel 3: out = A @ XL -------------------------------------
// C[1024,4096] = A[1024,1024] @ XL[1024,4096]; out[b*65536 + m*64 + o], c=b*64+o.
// Tile 128x128, BK=32, 256 threads, 8x8 per-thread register tile.
__global__ __launch_bounds__(256) void k_gemm(const float* __restrict__ A,
                                              const float* __restrict__ XL,
                                              float* __restrict__ out) {
  __shared__ float As[32][132];  // [k][m], padded
  __shared__ float Xs[32][132];  // [k][c], padded
  const int t = threadIdx.x;
  const int m0 = blockIdx.x * 128;
  const int c0 = blockIdx.y * 128;
  const int my8 = (t >> 4) * 8;
  const int cx8 = (t & 15) * 8;
  const int kk = t & 31;
  const int rr = t >> 5;  // 0..7
  float acc[8][8] = {};

  for (int k0 = 0; k0 < 1024; k0 += 32) {
#pragma unroll
    for (int s = 0; s < 16; ++s)
      As[kk][rr + 8 * s] = A[(size_t)(m0 + rr + 8 * s) * 1024 + k0 + kk];
#pragma unroll
    for (int s = 0; s < 4; ++s) {
      float4 f = *(const float4*)&XL[(size_t)(k0 + rr + 8 * s) * 4096 + c0 +
                                     kk * 4];
      *(float4*)&Xs[rr + 8 * s][kk * 4] = f;
    }
    __syncthreads();
#pragma unroll
    for (int k = 0; k < 32; ++k) {
      float a[8], xv[8];
      *(float4*)&a[0] = *(const float4*)&As[k][my8];
      *(float4*)&a[4] = *(const float4*)&As[k][my8 + 4];
      *(float4*)&xv[0] = *(const float4*)&Xs[k][cx8];
      *(float4*)&xv[4] = *(const float4*)&Xs[k][cx8 + 4];
#pragma unroll
      for (int i = 0; i < 8; ++i)
#pragma unroll
        for (int j = 0; j < 8; ++j) acc[i][j] += a[i] * xv[j];
    }
    __syncthreads();
  }

#pragma unroll
  for (int i = 0; i < 8; ++i) {
    const int m = m0 + my8 + i;
    const int c = c0 + cx8;
    const int bb = c >> 6, o = c & 63;
    float* dst = out + (size_t)bb * 65536 + (size_t)m * 64 + o;
    *(float4*)&dst[0] = *(float4*)&acc[i][0];
    *(float4*)&dst[4] = *(float4*)&acc[i][4];
  }
}

// ---------------- launcher ---------------------------------------------------
extern "C" void kernel_launch(void* const* d_in, const int* in_sizes, int n_in,
                              void* d_out, int out_size, void* d_ws,
                              size_t ws_size, hipStream_t stream) {
  (void)in_sizes;
  (void)n_in;
  (void)out_size;
  (void)ws_size;
  const float* x = (const float*)d_in[0];
  const float* Al = (const float*)d_in[1];
  const float* W1 = (const float*)d_in[2];
  const float* WV = (const float*)d_in[3];
  float* out = (float*)d_out;

  char* ws = (char*)d_ws;
  float* A = (float*)(ws);                                   // 4 MiB
  float* XL = (float*)(ws + (size_t)4 * 1024 * 1024);        // 16 MiB
  float* P = (float*)(ws + (size_t)20 * 1024 * 1024);        // 256 KiB
  float* v = (float*)(ws + (size_t)20 * 1024 * 1024 + 262144);  // 4 KiB
  unsigned* ctrl =
      (unsigned*)(ws + (size_t)20 * 1024 * 1024 + 262144 + 4096);

  hipMemsetAsync(ctrl, 0, 8, stream);
  hipLaunchKernelGGL(k_sinkA, dim3(64), dim3(1024), 0, stream, Al, A, P, v,
                     ctrl);
  hipLaunchKernelGGL(k_wpath, dim3(1024), dim3(256), 0, stream, x, W1, WV, XL);
  hipLaunchKernelGGL(k_gemm, dim3(8, 32), dim3(256), 0, stream, A, XL, out);
}

// Round 3
// 412.975 us; speedup vs baseline: 1.6699x; 1.6699x over previous
//
#include <hip/hip_runtime.h>
#include <hip/hip_bf16.h>

// KroneckerMixer: B=64, N=1024, K=64, BASIS=8, T=0.2, 20 sinkhorn iters.
// Pipeline (bf16 path, ws >= ~41 MB):
//   k_sinkA : multiplicative Sinkhorn-Knopp on exp(A_logits/T); relaxed-spin
//             grid barrier; coalesced partials. Emits Ah/Al bf16 hi/lo split
//             (fp32 A only on fallback path).
//   k_wpath : per-n local sinkhorn + x_local matmul -> XL fp32 [n][c].
//   k_xt    : transpose + hi/lo split XL -> XTh/XTl bf16 [c][n].
//   k_gemm3 : out[m][c] = Ah*XTh + Al*XTh + Ah*XTl via mfma_f32_16x16x32_bf16.
//             (Al*XTl term ~2^-18 — negligible.)
// Fallback (small ws): fp32 k_gemm as in R1.
//
// R3 fix: k_gemm3 staging covered only half the K-tile (16 of 32 ushorts per
// thread) -> uninitialized LDS -> NaN. Now 4x uint4 per operand per thread.

#define N_DIM 1024
#define INV_T 5.0f

typedef __attribute__((ext_vector_type(8))) short short8;
typedef __attribute__((ext_vector_type(4))) float float4v;

// ---------------- wave64 sum reduction via DPP (VALU pipe) -------------------
// Result valid in lane 63.
__device__ __forceinline__ float wave_red_sum(float x) {
#define DPP_ADD(C)                                                            \
  {                                                                           \
    int _y = __builtin_amdgcn_update_dpp(0, __float_as_int(x), (C), 0xf, 0xf, \
                                         true);                               \
    x += __int_as_float(_y);                                                  \
  }
  DPP_ADD(0x111);
  DPP_ADD(0x112);
  DPP_ADD(0x114);
  DPP_ADD(0x118);
  DPP_ADD(0x142);
  DPP_ADD(0x143);
#undef DPP_ADD
  return x;
}

// ---------------- grid barrier: relaxed spin, single acquire on exit ---------
__device__ __forceinline__ void gbar(unsigned* cnt, unsigned* gen,
                                     unsigned nblk) {
  __syncthreads();  // vmcnt(0) drain: all threads' stores issued to L2
  if (threadIdx.x == 0) {
    unsigned g =
        __hip_atomic_load(gen, __ATOMIC_RELAXED, __HIP_MEMORY_SCOPE_AGENT);
    // RELEASE: one wbl2 flush of our (coalesced, small) dirty lines.
    unsigned a = __hip_atomic_fetch_add(cnt, 1u, __ATOMIC_RELEASE,
                                        __HIP_MEMORY_SCOPE_AGENT);
    if (a == nblk - 1u) {
      __hip_atomic_store(cnt, 0u, __ATOMIC_RELAXED, __HIP_MEMORY_SCOPE_AGENT);
      __hip_atomic_fetch_add(gen, 1u, __ATOMIC_RELEASE,
                             __HIP_MEMORY_SCOPE_AGENT);
    } else {
      // RELAXED polls: scope bits on the load bypass stale cache lines,
      // no buffer_inv per iteration.
      while (__hip_atomic_load(gen, __ATOMIC_RELAXED,
                               __HIP_MEMORY_SCOPE_AGENT) == g)
        __builtin_amdgcn_s_sleep(1);
    }
    // Single ACQUIRE (one L1/L2 invalidate) so post-barrier reads are fresh.
    (void)__hip_atomic_load(gen, __ATOMIC_ACQUIRE, __HIP_MEMORY_SCOPE_AGENT);
  }
  __syncthreads();
}

// ---------------- kernel 1: A sinkhorn ---------------------------------------
// 64 blocks x 1024 threads. Block b owns rows r0..r0+15.
__global__ __launch_bounds__(1024) void k_sinkA(
    const float* __restrict__ L, float* __restrict__ A,
    __hip_bfloat16* __restrict__ Ah, __hip_bfloat16* __restrict__ Al,
    float* __restrict__ P, float* __restrict__ v, unsigned* __restrict__ ctrl,
    int write_bf16) {
  __shared__ float uS[16];
  const int t = threadIdx.x;
  const int b = blockIdx.x;  // 64
  const int r0 = b * 16;
  const int lane = t & 63;
  const int w = t >> 6;  // 0..15
  unsigned* cnt = ctrl;
  unsigned* gen = ctrl + 1;

  float e_c[16];
#pragma unroll
  for (int i = 0; i < 16; ++i)
    e_c[i] = __expf(L[(r0 + i) * N_DIM + t] * INV_T);

  float e_r[16];
  {
    const float4* src =
        (const float4*)(L + (size_t)(r0 + w) * N_DIM + lane * 16);
#pragma unroll
    for (int q = 0; q < 4; ++q) {
      float4 f = src[q];
      e_r[4 * q + 0] = __expf(f.x * INV_T);
      e_r[4 * q + 1] = __expf(f.y * INV_T);
      e_r[4 * q + 2] = __expf(f.z * INV_T);
      e_r[4 * q + 3] = __expf(f.w * INV_T);
    }
  }

  for (int it = 0; it < 20; ++it) {
    // ---- row pass: u_m = 1 / sum_n E0[m][n] * v[n]
    float p = 0.f;
    if (it == 0) {
#pragma unroll
      for (int j = 0; j < 16; ++j) p += e_r[j];
    } else {
      const float4* vv = (const float4*)(v + lane * 16);
#pragma unroll
      for (int q = 0; q < 4; ++q) {
        float4 f = vv[q];
        p += e_r[4 * q + 0] * f.x + e_r[4 * q + 1] * f.y +
             e_r[4 * q + 2] * f.z + e_r[4 * q + 3] * f.w;
      }
    }
    p = wave_red_sum(p);
    if (lane == 63) uS[w] = 1.0f / p;
    __syncthreads();
    // ---- col partials: COALESCED layout P[b][col]
    float cp = 0.f;
#pragma unroll
    for (int i = 0; i < 16; ++i) cp += e_c[i] * uS[i];
    P[b * N_DIM + t] = cp;
    gbar(cnt, gen, 64u);
    // ---- reduce partials: block b owns cols 16b..16b+15 (one per wave)
    {
      const int c = 16 * b + w;
      float s2 = P[lane * N_DIM + c];  // gather over partial index = lane
      s2 = wave_red_sum(s2);
      if (lane == 63) v[c] = 1.0f / s2;
    }
    gbar(cnt, gen, 64u);
  }
  // ---- final A = E0 * u (x) v  (bf16 hi/lo split for the MFMA gemm)
  const float vt = v[t];
#pragma unroll
  for (int i = 0; i < 16; ++i) {
    float a = e_c[i] * uS[i] * vt;
    if (write_bf16) {
      __hip_bfloat16 h = __float2bfloat16(a);
      Ah[(size_t)(r0 + i) * N_DIM + t] = h;
      Al[(size_t)(r0 + i) * N_DIM + t] =
          __float2bfloat16(a - __bfloat162float(h));
    } else {
      A[(size_t)(r0 + i) * N_DIM + t] = a;
    }
  }
}

// ---------------- kernel 2: W path + local mix -------------------------------
__global__ __launch_bounds__(256) void k_wpath(const float* __restrict__ x,
                                               const float* __restrict__ W1,
                                               const float* __restrict__ WV,
                                               float* __restrict__ XL) {
  __shared__ float uS[64];
  __shared__ float ps[4][64];
  __shared__ float Ws[64 * 64];
  __shared__ float Xs[64 * 65];
  const int n = blockIdx.x;
  const int t = threadIdx.x;
  const int lane = t & 63;
  const int h = t >> 6;

  float w1[8];
#pragma unroll
  for (int k = 0; k < 8; ++k) w1[k] = W1[n * 8 + k];

  float ew[16];
#pragma unroll
  for (int j = 0; j < 16; ++j) {
    const int f = j * 256 + t;
    float a = 0.f;
#pragma unroll
    for (int k = 0; k < 8; ++k) a += w1[k] * WV[k * 4096 + f];
    ew[j] = __expf(a * INV_T);
  }

  float vt = 1.0f;
  for (int it = 0; it < 20; ++it) {
#pragma unroll
    for (int j = 0; j < 16; ++j) {
      float p = wave_red_sum(ew[j] * vt);
      if (lane == 63) uS[4 * j + h] = 1.0f / p;
    }
    __syncthreads();
    float cp = 0.f;
#pragma unroll
    for (int j = 0; j < 16; ++j) cp += ew[j] * uS[4 * j + h];
    ps[h][lane] = cp;
    __syncthreads();
    vt = 1.0f / (ps[0][lane] + ps[1][lane] + ps[2][lane] + ps[3][lane]);
    __syncthreads();
  }

#pragma unroll
  for (int j = 0; j < 16; ++j)
    Ws[(4 * j + h) * 64 + lane] = ew[j] * uS[4 * j + h] * vt;
#pragma unroll
  for (int j = 0; j < 16; ++j) {
    const int bb = 4 * j + h;
    Xs[bb * 65 + lane] = x[(size_t)bb * 65536 + n * 64 + lane];
  }
  __syncthreads();

  const int o4 = (t & 15) * 4;
  const int b4 = (t >> 4) * 4;
  float acc[4][4] = {};
#pragma unroll 4
  for (int i = 0; i < 64; ++i) {
    float4 w4 = *(const float4*)&Ws[i * 64 + o4];
#pragma unroll
    for (int bb = 0; bb < 4; ++bb) {
      float xv = Xs[(b4 + bb) * 65 + i];
      acc[bb][0] += xv * w4.x;
      acc[bb][1] += xv * w4.y;
      acc[bb][2] += xv * w4.z;
      acc[bb][3] += xv * w4.w;
    }
  }
#pragma unroll
  for (int bb = 0; bb < 4; ++bb)
    *(float4*)&XL[(size_t)n * 4096 + (b4 + bb) * 64 + o4] =
        *(float4*)&acc[bb][0];
}

// ---------------- kernel 2b: transpose + hi/lo split -------------------------
// XL fp32 [n=1024][c=4096] -> XTh/XTl bf16 [c=4096][n=1024].
__global__ __launch_bounds__(256) void k_xt(const float* __restrict__ XL,
                                            __hip_bfloat16* __restrict__ XTh,
                                            __hip_bfloat16* __restrict__ XTl) {
  __shared__ float T[64 * 68];
  const int t = threadIdx.x;
  const int n0 = blockIdx.x * 64;
  const int c0 = blockIdx.y * 64;
  {
    const int r = t >> 4;         // 0..15
    const int c4 = (t & 15) * 4;  // 0..60
#pragma unroll
    for (int p = 0; p < 4; ++p) {
      float4 f =
          *(const float4*)&XL[(size_t)(n0 + r + 16 * p) * 4096 + c0 + c4];
      *(float4*)&T[(r + 16 * p) * 68 + c4] = f;
    }
  }
  __syncthreads();
  const int cl = t >> 2;        // 0..63
  const int nb = (t & 3) * 16;  // 0,16,32,48
  __align__(16) __hip_bfloat16 hbuf[16];
  __align__(16) __hip_bfloat16 lbuf[16];
#pragma unroll
  for (int j = 0; j < 16; ++j) {
    float xv = T[(nb + j) * 68 + cl];
    __hip_bfloat16 h = __float2bfloat16(xv);
    hbuf[j] = h;
    lbuf[j] = __float2bfloat16(xv - __bfloat162float(h));
  }
  const size_t off = (size_t)(c0 + cl) * 1024 + n0 + nb;
  *(uint4*)&XTh[off] = *(uint4*)&hbuf[0];
  *(uint4*)&XTh[off + 8] = *(uint4*)&hbuf[8];
  *(uint4*)&XTl[off] = *(uint4*)&lbuf[0];
  *(uint4*)&XTl[off + 8] = *(uint4*)&lbuf[8];
}

// ---------------- kernel 3 (bf16): out = Ah*XTh + Al*XTh + Ah*XTl ------------
// D[m=1024][c=4096], 128x128 block tile, 4 waves each 64x64 of 16x16x32 MFMA.
// Both operand arrays are [row][1024] bf16, K-contiguous (B^T GEMM pattern).
#define LSTR 72  // padded LDS row stride (elements)
__global__ __launch_bounds__(256) void k_gemm3(
    const ushort* __restrict__ Ah, const ushort* __restrict__ Al,
    const ushort* __restrict__ XTh, const ushort* __restrict__ XTl,
    float* __restrict__ out) {
  __shared__ ushort As[128 * LSTR];
  __shared__ ushort Xs[128 * LSTR];
  const int t = threadIdx.x;
  const int m0 = blockIdx.x * 128;
  const int c0 = blockIdx.y * 128;
  const int wid = t >> 6, lane = t & 63;
  const int wm = (wid & 1) * 64, wc = (wid >> 1) * 64;
  const int lm = lane & 15, q = lane >> 4;
  const int sr = t >> 1;        // staging row 0..127
  const int sc = (t & 1) * 32;  // staging k-offset: [sc, sc+32)

  float4v acc[4][4];
#pragma unroll
  for (int i = 0; i < 4; ++i)
#pragma unroll
    for (int j = 0; j < 4; ++j) acc[i][j] = (float4v){0.f, 0.f, 0.f, 0.f};

  for (int seg = 0; seg < 3; ++seg) {
    const ushort* Ag = (seg == 1) ? Al : Ah;
    const ushort* Xg = (seg == 2) ? XTl : XTh;
    for (int k0 = 0; k0 < 1024; k0 += 64) {
      __syncthreads();
      const ushort* ag = Ag + (size_t)(m0 + sr) * 1024 + k0 + sc;
      const ushort* xg = Xg + (size_t)(c0 + sr) * 1024 + k0 + sc;
      uint4 a0 = *(const uint4*)(ag);
      uint4 a1 = *(const uint4*)(ag + 8);
      uint4 a2 = *(const uint4*)(ag + 16);
      uint4 a3 = *(const uint4*)(ag + 24);
      uint4 x0 = *(const uint4*)(xg);
      uint4 x1 = *(const uint4*)(xg + 8);
      uint4 x2 = *(const uint4*)(xg + 16);
      uint4 x3 = *(const uint4*)(xg + 24);
      *(uint4*)&As[sr * LSTR + sc] = a0;
      *(uint4*)&As[sr * LSTR + sc + 8] = a1;
      *(uint4*)&As[sr * LSTR + sc + 16] = a2;
      *(uint4*)&As[sr * LSTR + sc + 24] = a3;
      *(uint4*)&Xs[sr * LSTR + sc] = x0;
      *(uint4*)&Xs[sr * LSTR + sc + 8] = x1;
      *(uint4*)&Xs[sr * LSTR + sc + 16] = x2;
      *(uint4*)&Xs[sr * LSTR + sc + 24] = x3;
      __syncthreads();
#pragma unroll
      for (int kk = 0; kk < 2; ++kk) {
        short8 af[4], xf[4];
#pragma unroll
        for (int i = 0; i < 4; ++i)
          af[i] = *(const short8*)&As[(wm + 16 * i + lm) * LSTR + kk * 32 +
                                      q * 8];
#pragma unroll
        for (int j = 0; j < 4; ++j)
          xf[j] = *(const short8*)&Xs[(wc + 16 * j + lm) * LSTR + kk * 32 +
                                      q * 8];
#pragma unroll
        for (int i = 0; i < 4; ++i)
#pragma unroll
          for (int j = 0; j < 4; ++j)
            acc[i][j] = __builtin_amdgcn_mfma_f32_16x16x32_bf16(
                af[i], xf[j], acc[i][j], 0, 0, 0);
      }
    }
  }
  // epilogue: D row = q*4 + reg, col = lm  (m89-verified C/D layout)
#pragma unroll
  for (int i = 0; i < 4; ++i) {
#pragma unroll
    for (int j = 0; j < 4; ++j) {
      const int m = m0 + wm + 16 * i + q * 4;
      const int c = c0 + wc + 16 * j + lm;
      const int bb = c >> 6, o = c & 63;
      float* dst = out + (size_t)bb * 65536 + (size_t)m * 64 + o;
#pragma unroll
      for (int r = 0; r < 4; ++r) dst[64 * r] = acc[i][j][r];
    }
  }
}

// ---------------- kernel 3 (fp32 fallback, R1 verbatim) ----------------------
__global__ __launch_bounds__(256) void k_gemm(const float* __restrict__ A,
                                              const float* __restrict__ XL,
                                              float* __restrict__ out) {
  __shared__ float Asm[32][132];
  __shared__ float Xsm[32][132];
  const int t = threadIdx.x;
  const int m0 = blockIdx.x * 128;
  const int c0 = blockIdx.y * 128;
  const int my8 = (t >> 4) * 8;
  const int cx8 = (t & 15) * 8;
  const int kk = t & 31;
  const int rr = t >> 5;
  float acc[8][8] = {};

  for (int k0 = 0; k0 < 1024; k0 += 32) {
#pragma unroll
    for (int s = 0; s < 16; ++s)
      Asm[kk][rr + 8 * s] = A[(size_t)(m0 + rr + 8 * s) * 1024 + k0 + kk];
#pragma unroll
    for (int s = 0; s < 4; ++s) {
      float4 f = *(const float4*)&XL[(size_t)(k0 + rr + 8 * s) * 4096 + c0 +
                                     kk * 4];
      *(float4*)&Xsm[rr + 8 * s][kk * 4] = f;
    }
    __syncthreads();
#pragma unroll
    for (int k = 0; k < 32; ++k) {
      float a[8], xv[8];
      *(float4*)&a[0] = *(const float4*)&Asm[k][my8];
      *(float4*)&a[4] = *(const float4*)&Asm[k][my8 + 4];
      *(float4*)&xv[0] = *(const float4*)&Xsm[k][cx8];
      *(float4*)&xv[4] = *(const float4*)&Xsm[k][cx8 + 4];
#pragma unroll
      for (int i = 0; i < 8; ++i)
#pragma unroll
        for (int j = 0; j < 8; ++j) acc[i][j] += a[i] * xv[j];
    }
    __syncthreads();
  }

#pragma unroll
  for (int i = 0; i < 8; ++i) {
    const int m = m0 + my8 + i;
    const int c = c0 + cx8;
    const int bb = c >> 6, o = c & 63;
    float* dst = out + (size_t)bb * 65536 + (size_t)m * 64 + o;
    *(float4*)&dst[0] = *(float4*)&acc[i][0];
    *(float4*)&dst[4] = *(float4*)&acc[i][4];
  }
}

// ---------------- launcher ---------------------------------------------------
extern "C" void kernel_launch(void* const* d_in, const int* in_sizes, int n_in,
                              void* d_out, int out_size, void* d_ws,
                              size_t ws_size, hipStream_t stream) {
  (void)in_sizes;
  (void)n_in;
  (void)out_size;
  const float* x = (const float*)d_in[0];
  const float* Alog = (const float*)d_in[1];
  const float* W1 = (const float*)d_in[2];
  const float* WV = (const float*)d_in[3];
  float* out = (float*)d_out;

  char* ws = (char*)d_ws;
  const size_t MB = 1024 * 1024;
  float* A = (float*)(ws);                        // 4 MB
  float* P = (float*)(ws + 4 * MB);               // 256 KB
  float* v = (float*)(ws + 4 * MB + 256 * 1024);  // 4 KB
  unsigned* ctrl = (unsigned*)(ws + 4 * MB + 260 * 1024);
  float* XL = (float*)(ws + 4 * MB + 512 * 1024);  // 16 MB -> ends 20.5 MB
  // bf16-path extras:
  __hip_bfloat16* Ah = (__hip_bfloat16*)(ws + 20 * MB + 512 * 1024);   // 2 MB
  __hip_bfloat16* Al = (__hip_bfloat16*)(ws + 22 * MB + 512 * 1024);   // 2 MB
  __hip_bfloat16* XTh = (__hip_bfloat16*)(ws + 24 * MB + 512 * 1024);  // 8 MB
  __hip_bfloat16* XTl = (__hip_bfloat16*)(ws + 32 * MB + 512 * 1024);  // 8 MB
  const bool use_bf16 = ws_size >= (40 * MB + 640 * 1024);

  hipMemsetAsync(ctrl, 0, 8, stream);
  hipLaunchKernelGGL(k_sinkA, dim3(64), dim3(1024), 0, stream, Alog, A, Ah, Al,
                     P, v, ctrl, use_bf16 ? 1 : 0);
  hipLaunchKernelGGL(k_wpath, dim3(1024), dim3(256), 0, stream, x, W1, WV, XL);
  if (use_bf16) {
    hipLaunchKernelGGL(k_xt, dim3(16, 64), dim3(256), 0, stream, XL, XTh, XTl);
    hipLaunchKernelGGL(k_gemm3, dim3(8, 32), dim3(256), 0, stream,
                       (const ushort*)Ah, (const ushort*)Al,
                       (const ushort*)XTh, (const ushort*)XTl, out);
  } else {
    hipLaunchKernelGGL(k_gemm, dim3(8, 32), dim3(256), 0, stream, A, XL, out);
  }
}